// Round 1
// baseline (1896.266 us; speedup 1.0000x reference)
//
#include <hip/hip_runtime.h>
#include <hip/hip_bf16.h>

typedef __bf16 bf16;
typedef __attribute__((ext_vector_type(4))) __bf16 bf16x4;
typedef __attribute__((ext_vector_type(8))) __bf16 bf16x8;
typedef __attribute__((ext_vector_type(4))) float f32x4;
typedef __attribute__((ext_vector_type(16))) float f32x16;

// Async global->LDS, 16B/lane. LDS dst is wave-uniform base; lane i lands at base + i*16.
__device__ __forceinline__ void async_load16(const bf16* g, const bf16* l) {
    __builtin_amdgcn_global_load_lds(
        (const __attribute__((address_space(1))) unsigned int*)g,
        (__attribute__((address_space(3))) unsigned int*)l,
        16, 0, 0);
}

// fp32 -> bf16, 8 elems/thread, exact-cover grid.
__global__ void cvt_bf16_kernel(const float* __restrict__ in, bf16* __restrict__ out) {
    const int i = blockIdx.x * blockDim.x + threadIdx.x;
    const f32x4* p = (const f32x4*)in + (size_t)i * 2;
    f32x4 a = p[0], b = p[1];
    bf16x8 o;
    o[0] = (bf16)a[0]; o[1] = (bf16)a[1]; o[2] = (bf16)a[2]; o[3] = (bf16)a[3];
    o[4] = (bf16)b[0]; o[5] = (bf16)b[1]; o[6] = (bf16)b[2]; o[7] = (bf16)b[3];
    *((bf16x8*)out + (size_t)i) = o;
}

// C = A(bf16) @ Weff^T, Weff = W .* (SU@SV), W/SU/SV fp32.
// NMAT==2: OUT(bf16) = silu(C0) * C1.  NMAT==1: OUT(fp32) = C0.
// Double-buffered LDS (1 barrier/K-step) + W reg-prefetch + source-swizzled sA
// (rule 21: linear LDS dest for global_load_lds, inverse-swizzled global src,
//  matching XOR on the ds_read side -> 16-way bank conflict reduced to 4-way).
template<int BM, int KDIM, int NMAT>
__global__ __launch_bounds__(256, 2)
void mlp_gemm(const bf16* __restrict__ A,
              const float* __restrict__ W0, const float* __restrict__ SU0, const float* __restrict__ SV0,
              const float* __restrict__ W1, const float* __restrict__ SU1, const float* __restrict__ SV1,
              void* __restrict__ OUTp, const int NT)
{
    constexpr int BK  = 32;
    constexpr int BN  = 32;
    constexpr int RPW = BM / 4;        // rows per wave
    constexpr int MI  = RPW / 32;      // 32x32 m-subtiles per wave
    constexpr int NLD = RPW / 16;      // async 16B-insts per thread for A tile
    constexpr int SBS = BK + 8;        // padded sB stride (80 B -> ~4-way on reads)
    constexpr int KIT = KDIM / BK;

    __shared__ bf16 sA[2][BM * BK];            // unpadded: global_load_lds target
    __shared__ bf16 sB[2][NMAT][BN * SBS];

    const int tid  = threadIdx.x;
    const int lane = tid & 63;
    const int wv   = tid >> 6;
    const int m0   = blockIdx.x * BM;          // m fastest -> W-tile reuse across m-blocks
    const int n0   = blockIdx.y * BN;

    // A staging: lane l -> LDS slot (row=l>>2, slot=l&3). Source swizzle: fetch
    // global seg (l&3) ^ ((l>>4)&3) so slot s of row r holds global seg s^((r>>2)&3).
    const int aseg = (lane & 3) ^ ((lane >> 4) & 3);
    const bf16* gA = A + (size_t)(m0 + wv * RPW + (lane >> 2)) * KDIM + aseg * 8;

    // W staging: 32 rows x 8 segs x 4 fp32
    const int brow = tid >> 3;
    const int bseg = tid & 7;
    const float* gW0  = W0 + (size_t)(n0 + brow) * KDIM + bseg * 4;
    const float* gSV0 = SV0 + bseg * 4;
    const f32x4  su0  = *(const f32x4*)(SU0 + (size_t)(n0 + brow) * 4);
    const float* gW1  = nullptr; const float* gSV1 = nullptr; f32x4 su1{};
    if constexpr (NMAT == 2) {
        gW1  = W1 + (size_t)(n0 + brow) * KDIM + bseg * 4;
        gSV1 = SV1 + bseg * 4;
        su1  = *(const f32x4*)(SU1 + (size_t)(n0 + brow) * 4);
    }
    const int sboff = brow * SBS + bseg * 4;

    f32x16 acc[NMAT][MI];
#pragma unroll
    for (int mt = 0; mt < NMAT; ++mt)
#pragma unroll
        for (int mi = 0; mi < MI; ++mi)
#pragma unroll
            for (int r = 0; r < 16; ++r)
                acc[mt][mi][r] = 0.0f;

    // W prefetch registers (double-buffered across iterations by program order)
    f32x4 w0r{}, s00{}, s01{}, s02{}, s03{};
    f32x4 w1r{}, s10{}, s11{}, s12{}, s13{};

    auto loadW = [&](int k0) {
        w0r = *(const f32x4*)(gW0 + k0);
        s00 = *(const f32x4*)(gSV0 + k0);
        s01 = *(const f32x4*)(gSV0 + KDIM + k0);
        s02 = *(const f32x4*)(gSV0 + 2 * KDIM + k0);
        s03 = *(const f32x4*)(gSV0 + 3 * KDIM + k0);
        if constexpr (NMAT == 2) {
            w1r = *(const f32x4*)(gW1 + k0);
            s10 = *(const f32x4*)(gSV1 + k0);
            s11 = *(const f32x4*)(gSV1 + KDIM + k0);
            s12 = *(const f32x4*)(gSV1 + 2 * KDIM + k0);
            s13 = *(const f32x4*)(gSV1 + 3 * KDIM + k0);
        }
    };

    auto stageA = [&](int k0, int buf) {
#pragma unroll
        for (int i = 0; i < NLD; ++i)
            async_load16(gA + (size_t)i * 16 * KDIM + k0,
                         &sA[buf][(wv * RPW + i * 16) * BK]);
    };

    auto dequant = [&](int buf) {
        bf16x4 ov;
#pragma unroll
        for (int j = 0; j < 4; ++j) {
            float sc = su0[0] * s00[j] + su0[1] * s01[j] + su0[2] * s02[j] + su0[3] * s03[j];
            ov[j] = (bf16)(w0r[j] * sc);
        }
        *(bf16x4*)&sB[buf][0][sboff] = ov;
        if constexpr (NMAT == 2) {
            bf16x4 ov1;
#pragma unroll
            for (int j = 0; j < 4; ++j) {
                float sc = su1[0] * s10[j] + su1[1] * s11[j] + su1[2] * s12[j] + su1[3] * s13[j];
                ov1[j] = (bf16)(w1r[j] * sc);
            }
            *(bf16x4*)&sB[buf][1][sboff] = ov1;
        }
    };

    // Read-side swizzle constants: global seg s lives in slot s ^ xr of its row.
    const int xr = ((lane & 31) >> 2) & 3;
    const int hi = lane >> 5;

    // ---- prologue: fill buffer 0 ----
    loadW(0);
    stageA(0, 0);
    dequant(0);          // waits W regs only (A asyncs stay in flight)
    __syncthreads();     // drains A asyncs

    for (int kt = 0; kt < KIT; ++kt) {
        const int cb = kt & 1, nb = cb ^ 1;
        const bool more = (kt + 1 < KIT);

        // Prefetch next tile: W -> regs, A -> other LDS buffer (async).
        if (more) {
            loadW((kt + 1) * BK);
            stageA((kt + 1) * BK, nb);
        }

        // MFMA 32x32x16 bf16. A/B frag: [idx=lane&31][k=(lane>>5)*8+j].
#pragma unroll
        for (int t = 0; t < BK / 16; ++t) {
            bf16x8 af[MI];
#pragma unroll
            for (int mi = 0; mi < MI; ++mi)
                af[mi] = *(const bf16x8*)(&sA[cb][(wv * RPW + mi * 32 + (lane & 31)) * BK
                                                  + (((t * 2 + hi) ^ xr) * 8)]);
#pragma unroll
            for (int mt = 0; mt < NMAT; ++mt) {
                bf16x8 bv = *(const bf16x8*)(&sB[cb][mt][(lane & 31) * SBS
                                                         + t * 16 + hi * 8]);
#pragma unroll
                for (int mi = 0; mi < MI; ++mi)
                    acc[mt][mi] = __builtin_amdgcn_mfma_f32_32x32x16_bf16(
                        af[mi], bv, acc[mt][mi], 0, 0, 0);
            }
        }

        // Dequant next W tile into the other buffer (reads prefetched regs).
        if (more) dequant(nb);

        __syncthreads();   // one barrier per K-step
    }

    // Epilogue. C/D: col=lane&31, row=(r&3)+8*(r>>2)+4*(lane>>5)  [m74/m101]
    const int cbl = lane & 31;
    const int rq  = (lane >> 5) * 4;
#pragma unroll
    for (int mi = 0; mi < MI; ++mi)
#pragma unroll
        for (int r = 0; r < 16; ++r) {
            const int row = m0 + wv * RPW + mi * 32 + rq + (r & 3) + ((r >> 2) << 3);
            const size_t idx = (size_t)row * NT + (n0 + cbl);
            if constexpr (NMAT == 2) {
                const float g = acc[0][mi][r];
                const float u = acc[1][mi][r];
                const float d = g / (1.0f + __expf(-g)) * u;   // silu(g)*u
                ((bf16*)OUTp)[idx] = (bf16)d;
            } else {
                ((float*)OUTp)[idx] = acc[0][mi][r];
            }
        }
}

extern "C" void kernel_launch(void* const* d_in, const int* in_sizes, int n_in,
                              void* d_out, int out_size, void* d_ws, size_t ws_size,
                              hipStream_t stream) {
    (void)in_sizes; (void)n_in; (void)out_size; (void)ws_size;

    const float* x   = (const float*)d_in[0];
    const float* gw  = (const float*)d_in[1];
    const float* gsu = (const float*)d_in[2];
    const float* gsv = (const float*)d_in[3];
    const float* uw  = (const float*)d_in[4];
    const float* usu = (const float*)d_in[5];
    const float* usv = (const float*)d_in[6];
    const float* dw  = (const float*)d_in[7];
    const float* dsu = (const float*)d_in[8];
    const float* dsv = (const float*)d_in[9];

    bf16* x_bf = (bf16*)d_ws;                              // [1024][4096]  (8 MB)
    bf16* d_sw = (bf16*)((char*)d_ws + (size_t)1024 * 4096 * 2);  // [1024][14336] (28 MB)
    float* out = (float*)d_out;                            // [1024][4096] fp32

    // K0: x -> bf16  (4.19M elems, 8/thread)
    cvt_bf16_kernel<<<2048, 256, 0, stream>>>(x, x_bf);

    // K1: fused gate+up+swiglu -> d_sw (bf16). m fastest for W-tile L2/L3 reuse.
    mlp_gemm<512, 4096, 2><<<dim3(2, 448), 256, 0, stream>>>(
        x_bf, gw, gsu, gsv, uw, usu, usv, d_sw, 14336);

    // K2: down -> out (fp32)
    mlp_gemm<512, 14336, 1><<<dim3(2, 128), 256, 0, stream>>>(
        d_sw, dw, dsu, dsv, nullptr, nullptr, nullptr, out, 4096);
}

// Round 2
// 1398.636 us; speedup vs baseline: 1.3558x; 1.3558x over previous
//
#include <hip/hip_runtime.h>
#include <hip/hip_bf16.h>

typedef __bf16 bf16;
typedef __attribute__((ext_vector_type(4))) __bf16 bf16x4;
typedef __attribute__((ext_vector_type(8))) __bf16 bf16x8;
typedef __attribute__((ext_vector_type(4))) float f32x4;
typedef __attribute__((ext_vector_type(16))) float f32x16;

// Async global->LDS, 16B/lane. LDS dst is wave-uniform base; lane i lands at base + i*16.
__device__ __forceinline__ void async_load16(const bf16* g, const bf16* l) {
    __builtin_amdgcn_global_load_lds(
        (const __attribute__((address_space(1))) unsigned int*)g,
        (__attribute__((address_space(3))) unsigned int*)l,
        16, 0, 0);
}

// fp32 -> bf16, 8 elems/thread, exact-cover grid.
__global__ void cvt_bf16_kernel(const float* __restrict__ in, bf16* __restrict__ out) {
    const int i = blockIdx.x * blockDim.x + threadIdx.x;
    const f32x4* p = (const f32x4*)in + (size_t)i * 2;
    f32x4 a = p[0], b = p[1];
    bf16x8 o;
    o[0] = (bf16)a[0]; o[1] = (bf16)a[1]; o[2] = (bf16)a[2]; o[3] = (bf16)a[3];
    o[4] = (bf16)b[0]; o[5] = (bf16)b[1]; o[6] = (bf16)b[2]; o[7] = (bf16)b[3];
    *((bf16x8*)out + (size_t)i) = o;
}

// W_eff[n][k] = W[n][k] * (SU[n,:] . SV[:,k]) -> bf16.  Memory-bound pre-pass.
// grid: (K/1024, N), block 256; thread handles one f32x4.
__global__ __launch_bounds__(256)
void dequant_kernel(const float* __restrict__ W, const float* __restrict__ SU,
                    const float* __restrict__ SV, bf16* __restrict__ out, const int K) {
    const int n  = blockIdx.y;
    const int c4 = blockIdx.x * blockDim.x + threadIdx.x;
    const size_t base = (size_t)n * K + (size_t)c4 * 4;
    f32x4 w  = *(const f32x4*)(W + base);
    f32x4 s0 = *(const f32x4*)(SV + (size_t)0 * K + c4 * 4);
    f32x4 s1 = *(const f32x4*)(SV + (size_t)1 * K + c4 * 4);
    f32x4 s2 = *(const f32x4*)(SV + (size_t)2 * K + c4 * 4);
    f32x4 s3 = *(const f32x4*)(SV + (size_t)3 * K + c4 * 4);
    f32x4 su = *(const f32x4*)(SU + (size_t)n * 4);
    bf16x4 o;
#pragma unroll
    for (int j = 0; j < 4; ++j) {
        float sc = su[0] * s0[j] + su[1] * s1[j] + su[2] * s2[j] + su[3] * s3[j];
        o[j] = (bf16)(w[j] * sc);
    }
    *(bf16x4*)(out + base) = o;
}

// Pure bf16 GEMM: C = A @ B^T, B pre-dequantized bf16 [N][KDIM].
// NMAT==2: OUT(bf16) = silu(C0) * C1.  NMAT==1: OUT(fp32) = C0.
// m97-style: both tiles via global_load_lds (linear LDS dest, source-swizzled
// per rule 21), double-buffered, one barrier per K-step.
// 256 thr = 4 waves. BN=64 (NI=2). Wave owns RPW=BM/4 rows x all BN cols.
template<int BM, int KDIM, int NMAT>
__global__ __launch_bounds__(256, 2)
void gemm_bf16(const bf16* __restrict__ A,
               const bf16* __restrict__ B0, const bf16* __restrict__ B1,
               void* __restrict__ OUTp, const int NT)
{
    constexpr int BK  = 32;
    constexpr int BN  = 64;
    constexpr int NI  = BN / 32;       // 2
    constexpr int RPW = BM / 4;
    constexpr int MI  = RPW / 32;
    constexpr int NLD = RPW / 16;      // A async insts per thread
    constexpr int KIT = KDIM / BK;

    __shared__ bf16 sA[2][BM * BK];          // linear: global_load_lds targets
    __shared__ bf16 sB[2][NMAT][BN * BK];

    const int tid  = threadIdx.x;
    const int lane = tid & 63;
    const int wv   = tid >> 6;
    const int m0   = blockIdx.x * BM;        // m fastest -> W-tile reuse in L2
    const int n0   = blockIdx.y * BN;

    // Staging map: lane l -> row (l>>2), 16B slot (l&3); fetch global seg
    // (l&3)^((l>>4)&3) so row r slot s holds seg s^((r>>2)&3)  [rule 21].
    const int aseg = (lane & 3) ^ ((lane >> 4) & 3);
    const bf16* gA  = A  + (size_t)(m0 + wv * RPW + (lane >> 2)) * KDIM + aseg * 8;
    const bf16* gB0 = B0 + (size_t)(n0 + wv * 16 + (lane >> 2)) * KDIM + aseg * 8;
    const bf16* gB1 = nullptr;
    if constexpr (NMAT == 2)
        gB1 = B1 + (size_t)(n0 + wv * 16 + (lane >> 2)) * KDIM + aseg * 8;

    f32x16 acc[NMAT][NI][MI];
#pragma unroll
    for (int mt = 0; mt < NMAT; ++mt)
#pragma unroll
        for (int ni = 0; ni < NI; ++ni)
#pragma unroll
            for (int mi = 0; mi < MI; ++mi)
#pragma unroll
                for (int r = 0; r < 16; ++r)
                    acc[mt][ni][mi][r] = 0.0f;

    auto stage = [&](int k0, int buf) {
#pragma unroll
        for (int i = 0; i < NLD; ++i)
            async_load16(gA + (size_t)i * 16 * KDIM + k0,
                         &sA[buf][(wv * RPW + i * 16) * BK]);
        async_load16(gB0 + k0, &sB[buf][0][(wv * 16) * BK]);
        if constexpr (NMAT == 2)
            async_load16(gB1 + k0, &sB[buf][1][(wv * 16) * BK]);
    };

    // Read-side swizzle: global seg s of row r lives at slot s^((r>>2)&3).
    const int il = lane & 31;
    const int xr = (il >> 2) & 3;
    const int hi = lane >> 5;

    stage(0, 0);
    __syncthreads();

    for (int kt = 0; kt < KIT; ++kt) {
        const int cb = kt & 1, nb = cb ^ 1;
        if (kt + 1 < KIT) stage((kt + 1) * BK, nb);

        // MFMA 32x32x16 bf16. A/B frag: [idx=lane&31][k=(lane>>5)*8+j].
#pragma unroll
        for (int t = 0; t < BK / 16; ++t) {
            const int ksl = ((t * 2 + hi) ^ xr) * 8;
            bf16x8 af[MI];
#pragma unroll
            for (int mi = 0; mi < MI; ++mi)
                af[mi] = *(const bf16x8*)(&sA[cb][(wv * RPW + mi * 32 + il) * BK + ksl]);
#pragma unroll
            for (int mt = 0; mt < NMAT; ++mt)
#pragma unroll
                for (int ni = 0; ni < NI; ++ni) {
                    bf16x8 bv = *(const bf16x8*)(&sB[cb][mt][(ni * 32 + il) * BK + ksl]);
#pragma unroll
                    for (int mi = 0; mi < MI; ++mi)
                        acc[mt][ni][mi] = __builtin_amdgcn_mfma_f32_32x32x16_bf16(
                            af[mi], bv, acc[mt][ni][mi], 0, 0, 0);
                }
        }
        __syncthreads();
    }

    // Epilogue. C/D: col=lane&31, row=(r&3)+8*(r>>2)+4*(lane>>5)  [m74/m101]
    const int rq = hi * 4;
#pragma unroll
    for (int ni = 0; ni < NI; ++ni)
#pragma unroll
        for (int mi = 0; mi < MI; ++mi)
#pragma unroll
            for (int r = 0; r < 16; ++r) {
                const int row = m0 + wv * RPW + mi * 32 + rq + (r & 3) + ((r >> 2) << 3);
                const size_t idx = (size_t)row * NT + (n0 + ni * 32 + il);
                if constexpr (NMAT == 2) {
                    const float g = acc[0][ni][mi][r];
                    const float u = acc[1][ni][mi][r];
                    ((bf16*)OUTp)[idx] = (bf16)(g / (1.0f + __expf(-g)) * u);
                } else {
                    ((float*)OUTp)[idx] = acc[0][ni][mi][r];
                }
            }
}

// ---------------- Fallback (fused dequant) path, unchanged from R1 ----------------
template<int BM, int KDIM, int NMAT>
__global__ __launch_bounds__(256, 2)
void mlp_gemm(const bf16* __restrict__ A,
              const float* __restrict__ W0, const float* __restrict__ SU0, const float* __restrict__ SV0,
              const float* __restrict__ W1, const float* __restrict__ SU1, const float* __restrict__ SV1,
              void* __restrict__ OUTp, const int NT)
{
    constexpr int BK  = 32;
    constexpr int BN  = 32;
    constexpr int RPW = BM / 4;
    constexpr int MI  = RPW / 32;
    constexpr int NLD = RPW / 16;
    constexpr int SBS = BK + 8;
    constexpr int KIT = KDIM / BK;

    __shared__ bf16 sA[2][BM * BK];
    __shared__ bf16 sB[2][NMAT][BN * SBS];

    const int tid  = threadIdx.x;
    const int lane = tid & 63;
    const int wv   = tid >> 6;
    const int m0   = blockIdx.x * BM;
    const int n0   = blockIdx.y * BN;

    const int aseg = (lane & 3) ^ ((lane >> 4) & 3);
    const bf16* gA = A + (size_t)(m0 + wv * RPW + (lane >> 2)) * KDIM + aseg * 8;

    const int brow = tid >> 3;
    const int bseg = tid & 7;
    const float* gW0  = W0 + (size_t)(n0 + brow) * KDIM + bseg * 4;
    const float* gSV0 = SV0 + bseg * 4;
    const f32x4  su0  = *(const f32x4*)(SU0 + (size_t)(n0 + brow) * 4);
    const float* gW1  = nullptr; const float* gSV1 = nullptr; f32x4 su1{};
    if constexpr (NMAT == 2) {
        gW1  = W1 + (size_t)(n0 + brow) * KDIM + bseg * 4;
        gSV1 = SV1 + bseg * 4;
        su1  = *(const f32x4*)(SU1 + (size_t)(n0 + brow) * 4);
    }
    const int sboff = brow * SBS + bseg * 4;

    f32x16 acc[NMAT][MI];
#pragma unroll
    for (int mt = 0; mt < NMAT; ++mt)
#pragma unroll
        for (int mi = 0; mi < MI; ++mi)
#pragma unroll
            for (int r = 0; r < 16; ++r)
                acc[mt][mi][r] = 0.0f;

    f32x4 w0r{}, s00{}, s01{}, s02{}, s03{};
    f32x4 w1r{}, s10{}, s11{}, s12{}, s13{};

    auto loadW = [&](int k0) {
        w0r = *(const f32x4*)(gW0 + k0);
        s00 = *(const f32x4*)(gSV0 + k0);
        s01 = *(const f32x4*)(gSV0 + KDIM + k0);
        s02 = *(const f32x4*)(gSV0 + 2 * KDIM + k0);
        s03 = *(const f32x4*)(gSV0 + 3 * KDIM + k0);
        if constexpr (NMAT == 2) {
            w1r = *(const f32x4*)(gW1 + k0);
            s10 = *(const f32x4*)(gSV1 + k0);
            s11 = *(const f32x4*)(gSV1 + KDIM + k0);
            s12 = *(const f32x4*)(gSV1 + 2 * KDIM + k0);
            s13 = *(const f32x4*)(gSV1 + 3 * KDIM + k0);
        }
    };

    auto stageA = [&](int k0, int buf) {
#pragma unroll
        for (int i = 0; i < NLD; ++i)
            async_load16(gA + (size_t)i * 16 * KDIM + k0,
                         &sA[buf][(wv * RPW + i * 16) * BK]);
    };

    auto dequant = [&](int buf) {
        bf16x4 ov;
#pragma unroll
        for (int j = 0; j < 4; ++j) {
            float sc = su0[0] * s00[j] + su0[1] * s01[j] + su0[2] * s02[j] + su0[3] * s03[j];
            ov[j] = (bf16)(w0r[j] * sc);
        }
        *(bf16x4*)&sB[buf][0][sboff] = ov;
        if constexpr (NMAT == 2) {
            bf16x4 ov1;
#pragma unroll
            for (int j = 0; j < 4; ++j) {
                float sc = su1[0] * s10[j] + su1[1] * s11[j] + su1[2] * s12[j] + su1[3] * s13[j];
                ov1[j] = (bf16)(w1r[j] * sc);
            }
            *(bf16x4*)&sB[buf][1][sboff] = ov1;
        }
    };

    const int xr = ((lane & 31) >> 2) & 3;
    const int hi = lane >> 5;

    loadW(0);
    stageA(0, 0);
    dequant(0);
    __syncthreads();

    for (int kt = 0; kt < KIT; ++kt) {
        const int cb = kt & 1, nb = cb ^ 1;
        const bool more = (kt + 1 < KIT);

        if (more) {
            loadW((kt + 1) * BK);
            stageA((kt + 1) * BK, nb);
        }

#pragma unroll
        for (int t = 0; t < BK / 16; ++t) {
            bf16x8 af[MI];
#pragma unroll
            for (int mi = 0; mi < MI; ++mi)
                af[mi] = *(const bf16x8*)(&sA[cb][(wv * RPW + mi * 32 + (lane & 31)) * BK
                                                  + (((t * 2 + hi) ^ xr) * 8)]);
#pragma unroll
            for (int mt = 0; mt < NMAT; ++mt) {
                bf16x8 bv = *(const bf16x8*)(&sB[cb][mt][(lane & 31) * SBS
                                                         + t * 16 + hi * 8]);
#pragma unroll
                for (int mi = 0; mi < MI; ++mi)
                    acc[mt][mi] = __builtin_amdgcn_mfma_f32_32x32x16_bf16(
                        af[mi], bv, acc[mt][mi], 0, 0, 0);
            }
        }

        if (more) dequant(nb);
        __syncthreads();
    }

    const int cbl = lane & 31;
    const int rq  = (lane >> 5) * 4;
#pragma unroll
    for (int mi = 0; mi < MI; ++mi)
#pragma unroll
        for (int r = 0; r < 16; ++r) {
            const int row = m0 + wv * RPW + mi * 32 + rq + (r & 3) + ((r >> 2) << 3);
            const size_t idx = (size_t)row * NT + (n0 + cbl);
            if constexpr (NMAT == 2) {
                const float g = acc[0][mi][r];
                const float u = acc[1][mi][r];
                const float d = g / (1.0f + __expf(-g)) * u;
                ((bf16*)OUTp)[idx] = (bf16)d;
            } else {
                ((float*)OUTp)[idx] = acc[0][mi][r];
            }
        }
}

extern "C" void kernel_launch(void* const* d_in, const int* in_sizes, int n_in,
                              void* d_out, int out_size, void* d_ws, size_t ws_size,
                              hipStream_t stream) {
    (void)in_sizes; (void)n_in; (void)out_size;

    const float* x   = (const float*)d_in[0];
    const float* gw  = (const float*)d_in[1];
    const float* gsu = (const float*)d_in[2];
    const float* gsv = (const float*)d_in[3];
    const float* uw  = (const float*)d_in[4];
    const float* usu = (const float*)d_in[5];
    const float* usv = (const float*)d_in[6];
    const float* dw  = (const float*)d_in[7];
    const float* dsu = (const float*)d_in[8];
    const float* dsv = (const float*)d_in[9];

    const size_t XBF = (size_t)1024 * 4096 * 2;     // x in bf16
    const size_t DSW = (size_t)1024 * 14336 * 2;    // swiglu out, bf16
    const size_t WSZ = (size_t)14336 * 4096 * 2;    // one dequantized weight matrix
    const size_t REQ = XBF + DSW + 3 * WSZ;         // ~372 MB

    bf16* x_bf = (bf16*)d_ws;
    bf16* d_sw = (bf16*)((char*)d_ws + XBF);
    float* out = (float*)d_out;

    // K0: x -> bf16  (4.19M elems, 8/thread)
    cvt_bf16_kernel<<<2048, 256, 0, stream>>>(x, x_bf);

    if (ws_size >= REQ) {
        bf16* Wg = (bf16*)((char*)d_ws + XBF + DSW);
        bf16* Wu = (bf16*)((char*)Wg + WSZ);
        bf16* Wd = (bf16*)((char*)Wu + WSZ);

        // Pre-pass: dequantize all three weight matrices to bf16 (memory-bound).
        dequant_kernel<<<dim3(4, 14336), 256, 0, stream>>>(gw, gsu, gsv, Wg, 4096);
        dequant_kernel<<<dim3(4, 14336), 256, 0, stream>>>(uw, usu, usv, Wu, 4096);
        dequant_kernel<<<dim3(14, 4096), 256, 0, stream>>>(dw, dsu, dsv, Wd, 14336);

        // K1: fused gate+up+swiglu. BM=256, BN=64 -> grid (4,224)=896 blocks.
        gemm_bf16<256, 4096, 2><<<dim3(4, 224), 256, 0, stream>>>(
            x_bf, Wg, Wu, d_sw, 14336);

        // K2: down. BM=128, BN=64 -> grid (8,64)=512 blocks (2/CU).
        gemm_bf16<128, 14336, 1><<<dim3(8, 64), 256, 0, stream>>>(
            d_sw, Wd, nullptr, out, 4096);
    } else {
        // Fallback: fused-dequant path (workspace too small for weight pre-pass).
        mlp_gemm<512, 4096, 2><<<dim3(2, 448), 256, 0, stream>>>(
            x_bf, gw, gsu, gsv, uw, usu, usv, d_sw, 14336);
        mlp_gemm<512, 14336, 1><<<dim3(2, 128), 256, 0, stream>>>(
            d_sw, dw, dsu, dsv, nullptr, nullptr, nullptr, out, 4096);
    }
}

// Round 7
// 1206.190 us; speedup vs baseline: 1.5721x; 1.1595x over previous
//
#include <hip/hip_runtime.h>
#include <hip/hip_bf16.h>

typedef __bf16 bf16;
typedef __attribute__((ext_vector_type(4))) __bf16 bf16x4;
typedef __attribute__((ext_vector_type(8))) __bf16 bf16x8;
typedef __attribute__((ext_vector_type(4))) float f32x4;
typedef __attribute__((ext_vector_type(16))) float f32x16;

// Async global->LDS, 16B/lane. LDS dst is wave-uniform base; lane i lands at base + i*16.
__device__ __forceinline__ void async_load16(const bf16* g, const bf16* l) {
    __builtin_amdgcn_global_load_lds(
        (const __attribute__((address_space(1))) unsigned int*)g,
        (__attribute__((address_space(3))) unsigned int*)l,
        16, 0, 0);
}

template<int N>
__device__ __forceinline__ void wait_vmcnt() {
    asm volatile("s_waitcnt vmcnt(%0)" :: "n"(N) : "memory");
}
__device__ __forceinline__ void fence_lgkm0() {
    asm volatile("s_waitcnt lgkmcnt(0)" ::: "memory");
}
// HW barrier that is ALSO a compiler memory fence (builtin s_barrier is not:
// without the clobber, ds_reads of other waves' staged data can be scheduled
// into the window between the vmcnt wait and the barrier -> cross-wave race).
__device__ __forceinline__ void barrier_mem() {
    asm volatile("s_barrier" ::: "memory");
}

// fp32 -> bf16, 8 elems/thread, exact-cover grid.
__global__ void cvt_bf16_kernel(const float* __restrict__ in, bf16* __restrict__ out) {
    const int i = blockIdx.x * blockDim.x + threadIdx.x;
    const f32x4* p = (const f32x4*)in + (size_t)i * 2;
    f32x4 a = p[0], b = p[1];
    bf16x8 o;
    o[0] = (bf16)a[0]; o[1] = (bf16)a[1]; o[2] = (bf16)a[2]; o[3] = (bf16)a[3];
    o[4] = (bf16)b[0]; o[5] = (bf16)b[1]; o[6] = (bf16)b[2]; o[7] = (bf16)b[3];
    *((bf16x8*)out + (size_t)i) = o;
}

// W_eff[n][k] = W[n][k] * (SU[n,:] . SV[:,k]) -> bf16.  Memory-bound pre-pass.
__global__ __launch_bounds__(256)
void dequant_kernel(const float* __restrict__ W, const float* __restrict__ SU,
                    const float* __restrict__ SV, bf16* __restrict__ out, const int K) {
    const int n  = blockIdx.y;
    const int c4 = blockIdx.x * blockDim.x + threadIdx.x;
    const size_t base = (size_t)n * K + (size_t)c4 * 4;
    f32x4 w  = *(const f32x4*)(W + base);
    f32x4 s0 = *(const f32x4*)(SV + (size_t)0 * K + c4 * 4);
    f32x4 s1 = *(const f32x4*)(SV + (size_t)1 * K + c4 * 4);
    f32x4 s2 = *(const f32x4*)(SV + (size_t)2 * K + c4 * 4);
    f32x4 s3 = *(const f32x4*)(SV + (size_t)3 * K + c4 * 4);
    f32x4 su = *(const f32x4*)(SU + (size_t)n * 4);
    bf16x4 o;
#pragma unroll
    for (int j = 0; j < 4; ++j) {
        float sc = su[0] * s0[j] + su[1] * s1[j] + su[2] * s2[j] + su[3] * s3[j];
        o[j] = (bf16)(w[j] * sc);
    }
    *(bf16x4*)(out + base) = o;
}

// Pure bf16 GEMM: C = A @ B^T, B pre-dequantized bf16 [N][KDIM].
// NMAT==2: OUT(bf16) = silu(C0) * C1.  NMAT==1: OUT(fp32) = C0.
// T3+T4: NBUF-deep circular LDS buffer, asm s_barrier (memory-fencing), counted
// vmcnt (never 0 in steady state; tail iterations use the exact remaining-loads
// count -- waiting the steady-state N when fewer loads are outstanding would
// NOT drain tile kt).
// T1: XCD-chunked block swizzle (requires gridDim.x % 8 == 0).
// Source-swizzled staging (rule 21): linear LDS dest for global_load_lds,
// inverse-swizzled global src, matching XOR on ds_read (0 conflicts measured).
template<int BM, int BK, int KDIM, int NMAT, int NBUF, int GXLOG>
__global__ __launch_bounds__(256, 2)
void gemm_bf16(const bf16* __restrict__ A,
               const bf16* __restrict__ B0, const bf16* __restrict__ B1,
               void* __restrict__ OUTp, const int NT)
{
    constexpr int BN    = 64;
    constexpr int NI    = 2;            // 32-col subtiles per wave
    constexpr int RPW   = BM / 4;       // rows per wave
    constexpr int MI    = RPW / 32;     // 32-row subtiles per wave
    constexpr int SEGS  = BK / 8;       // 16B segments per row
    constexpr int RPI   = 64 / SEGS;    // rows per async inst
    constexpr int NLD   = RPW / RPI;    // A async insts / thread / tile
    constexpr int BLD   = 16 / RPI;     // B async insts / thread / mat / tile
    constexpr int LTOT  = NLD + NMAT * BLD;
    constexpr int KIT   = KDIM / BK;
    static_assert(NBUF >= 2 && NBUF <= 4, "wait chain covers NBUF 2..4");
    static_assert(NBUF * LTOT <= 63, "vmcnt range");

    __shared__ __align__(16) bf16 sA[NBUF][BM * BK];
    __shared__ __align__(16) bf16 sB[NBUF][NMAT][BN * BK];

    const int tid  = threadIdx.x;
    const int lane = tid & 63;
    const int wv   = tid >> 6;

    // T1: chunked XCD swizzle. hw id h lands on XCD h%8; logical ids contiguous per XCD.
    const int nwg = gridDim.x;
    const int lid = (blockIdx.x & 7) * (nwg >> 3) + (blockIdx.x >> 3);
    const int m0  = (lid & ((1 << GXLOG) - 1)) * BM;   // m fastest -> weight reuse in-XCD
    const int n0  = (lid >> GXLOG) * BN;

    // Staging map: lane -> (row srow, 16B slot sseg); fetch from swizzled global seg.
    const int srow = lane / SEGS;
    const int sseg = lane % SEGS;
    int aseg;
    if constexpr (BK == 32) aseg = sseg ^ ((lane >> 4) & 3);   // key (row>>2)&3
    else                    aseg = sseg ^ (srow & 7);          // key row&7

    const bf16* gA  = A  + (size_t)(m0 + wv * RPW + srow) * KDIM + aseg * 8;
    const bf16* gB0 = B0 + (size_t)(n0 + wv * 16  + srow) * KDIM + aseg * 8;
    const bf16* gB1 = nullptr;
    if constexpr (NMAT == 2)
        gB1 = B1 + (size_t)(n0 + wv * 16 + srow) * KDIM + aseg * 8;

    f32x16 acc[NMAT][NI][MI];
#pragma unroll
    for (int mt = 0; mt < NMAT; ++mt)
#pragma unroll
        for (int ni = 0; ni < NI; ++ni)
#pragma unroll
            for (int mi = 0; mi < MI; ++mi)
#pragma unroll
                for (int r = 0; r < 16; ++r)
                    acc[mt][ni][mi][r] = 0.0f;

    auto stage = [&](int kt, int buf) {
        const int k0 = kt * BK;
#pragma unroll
        for (int i = 0; i < NLD; ++i)
            async_load16(gA + (size_t)i * RPI * KDIM + k0,
                         &sA[buf][(wv * RPW + i * RPI) * BK]);
#pragma unroll
        for (int j = 0; j < BLD; ++j) {
            async_load16(gB0 + (size_t)j * RPI * KDIM + k0,
                         &sB[buf][0][(wv * 16 + j * RPI) * BK]);
            if constexpr (NMAT == 2)
                async_load16(gB1 + (size_t)j * RPI * KDIM + k0,
                             &sB[buf][1][(wv * 16 + j * RPI) * BK]);
        }
    };

    // Wait until tile kt's loads have landed: outstanding must drop to
    // (tiles staged beyond kt) * LTOT. rem = KIT-1-kt, capped at NBUF-1.
    auto wait_tile = [&](int rem) {
        if (rem >= NBUF - 1) { wait_vmcnt<(NBUF - 1) * LTOT>(); return; }
        if constexpr (NBUF >= 4) { if (rem == 2) { wait_vmcnt<2 * LTOT>(); return; } }
        if constexpr (NBUF >= 3) { if (rem == 1) { wait_vmcnt<1 * LTOT>(); return; } }
        wait_vmcnt<0>();
    };

    // Read-side swizzle key (consistent for A and B rows; offsets are mult. of 32).
    const int il = lane & 31;
    const int hi = lane >> 5;
    int xrk;
    if constexpr (BK == 32) xrk = (il >> 2) & 3;
    else                    xrk = il & 7;

    // ---- prologue: fill all NBUF buffers, keep everything in flight ----
#pragma unroll
    for (int p = 0; p < NBUF; ++p) stage(p, p);

    int cb = 0;
    for (int kt = 0; kt < KIT; ++kt) {
        wait_tile(KIT - 1 - kt);             // tile kt landed (per-wave); rest in flight
        barrier_mem();                       // all waves: tile kt ready

        // MFMA 32x32x16 bf16. A/B frag: [idx=lane&31][k=(lane>>5)*8+j].
#pragma unroll
        for (int t = 0; t < BK / 16; ++t) {
            const int ksl = ((t * 2 + hi) ^ xrk) * 8;
            bf16x8 af[MI];
#pragma unroll
            for (int mi = 0; mi < MI; ++mi)
                af[mi] = *(const bf16x8*)(&sA[cb][(wv * RPW + mi * 32 + il) * BK + ksl]);
#pragma unroll
            for (int mt = 0; mt < NMAT; ++mt)
#pragma unroll
                for (int ni = 0; ni < NI; ++ni) {
                    bf16x8 bv = *(const bf16x8*)(&sB[cb][mt][(ni * 32 + il) * BK + ksl]);
#pragma unroll
                    for (int mi = 0; mi < MI; ++mi)
                        acc[mt][ni][mi] = __builtin_amdgcn_mfma_f32_32x32x16_bf16(
                            af[mi], bv, acc[mt][ni][mi], 0, 0, 0);
                }
        }

        fence_lgkm0();                       // my ds_reads complete (data in regs)
        barrier_mem();                       // all waves' reads done -> safe to overwrite
        if (kt + NBUF < KIT) stage(kt + NBUF, cb);
        cb = (cb + 1 == NBUF) ? 0 : cb + 1;
    }

    // Epilogue. C/D: col=lane&31, row=(r&3)+8*(r>>2)+4*(lane>>5)  [m74/m101]
    const int rq = hi * 4;
#pragma unroll
    for (int ni = 0; ni < NI; ++ni)
#pragma unroll
        for (int mi = 0; mi < MI; ++mi)
#pragma unroll
            for (int r = 0; r < 16; ++r) {
                const int row = m0 + wv * RPW + mi * 32 + rq + (r & 3) + ((r >> 2) << 3);
                const size_t idx = (size_t)row * NT + (n0 + ni * 32 + il);
                if constexpr (NMAT == 2) {
                    const float g = acc[0][ni][mi][r];
                    const float u = acc[1][ni][mi][r];
                    ((bf16*)OUTp)[idx] = (bf16)(g / (1.0f + __expf(-g)) * u);
                } else {
                    ((float*)OUTp)[idx] = acc[0][ni][mi][r];
                }
            }
}

// ---------------- Fallback (fused dequant) path ----------------
template<int BM, int KDIM, int NMAT>
__global__ __launch_bounds__(256, 2)
void mlp_gemm(const bf16* __restrict__ A,
              const float* __restrict__ W0, const float* __restrict__ SU0, const float* __restrict__ SV0,
              const float* __restrict__ W1, const float* __restrict__ SU1, const float* __restrict__ SV1,
              void* __restrict__ OUTp, const int NT)
{
    constexpr int BK  = 32;
    constexpr int BN  = 32;
    constexpr int RPW = BM / 4;
    constexpr int MI  = RPW / 32;
    constexpr int NLD = RPW / 16;
    constexpr int SBS = BK + 8;
    constexpr int KIT = KDIM / BK;

    __shared__ bf16 sA[2][BM * BK];
    __shared__ bf16 sB[2][NMAT][BN * SBS];

    const int tid  = threadIdx.x;
    const int lane = tid & 63;
    const int wv   = tid >> 6;
    const int m0   = blockIdx.x * BM;
    const int n0   = blockIdx.y * BN;

    const int aseg = (lane & 3) ^ ((lane >> 4) & 3);
    const bf16* gA = A + (size_t)(m0 + wv * RPW + (lane >> 2)) * KDIM + aseg * 8;

    const int brow = tid >> 3;
    const int bseg = tid & 7;
    const float* gW0  = W0 + (size_t)(n0 + brow) * KDIM + bseg * 4;
    const float* gSV0 = SV0 + bseg * 4;
    const f32x4  su0  = *(const f32x4*)(SU0 + (size_t)(n0 + brow) * 4);
    const float* gW1  = nullptr; const float* gSV1 = nullptr; f32x4 su1{};
    if constexpr (NMAT == 2) {
        gW1  = W1 + (size_t)(n0 + brow) * KDIM + bseg * 4;
        gSV1 = SV1 + bseg * 4;
        su1  = *(const f32x4*)(SU1 + (size_t)(n0 + brow) * 4);
    }
    const int sboff = brow * SBS + bseg * 4;

    f32x16 acc[NMAT][MI];
#pragma unroll
    for (int mt = 0; mt < NMAT; ++mt)
#pragma unroll
        for (int mi = 0; mi < MI; ++mi)
#pragma unroll
            for (int r = 0; r < 16; ++r)
                acc[mt][mi][r] = 0.0f;

    f32x4 w0r{}, s00{}, s01{}, s02{}, s03{};
    f32x4 w1r{}, s10{}, s11{}, s12{}, s13{};

    auto loadW = [&](int k0) {
        w0r = *(const f32x4*)(gW0 + k0);
        s00 = *(const f32x4*)(gSV0 + k0);
        s01 = *(const f32x4*)(gSV0 + KDIM + k0);
        s02 = *(const f32x4*)(gSV0 + 2 * KDIM + k0);
        s03 = *(const f32x4*)(gSV0 + 3 * KDIM + k0);
        if constexpr (NMAT == 2) {
            w1r = *(const f32x4*)(gW1 + k0);
            s10 = *(const f32x4*)(gSV1 + k0);
            s11 = *(const f32x4*)(gSV1 + KDIM + k0);
            s12 = *(const f32x4*)(gSV1 + 2 * KDIM + k0);
            s13 = *(const f32x4*)(gSV1 + 3 * KDIM + k0);
        }
    };

    auto stageA = [&](int k0, int buf) {
#pragma unroll
        for (int i = 0; i < NLD; ++i)
            async_load16(gA + (size_t)i * 16 * KDIM + k0,
                         &sA[buf][(wv * RPW + i * 16) * BK]);
    };

    auto dequant = [&](int buf) {
        bf16x4 ov;
#pragma unroll
        for (int j = 0; j < 4; ++j) {
            float sc = su0[0] * s00[j] + su0[1] * s01[j] + su0[2] * s02[j] + su0[3] * s03[j];
            ov[j] = (bf16)(w0r[j] * sc);
        }
        *(bf16x4*)&sB[buf][0][sboff] = ov;
        if constexpr (NMAT == 2) {
            bf16x4 ov1;
#pragma unroll
            for (int j = 0; j < 4; ++j) {
                float sc = su1[0] * s10[j] + su1[1] * s11[j] + su1[2] * s12[j] + su1[3] * s13[j];
                ov1[j] = (bf16)(w1r[j] * sc);
            }
            *(bf16x4*)&sB[buf][1][sboff] = ov1;
        }
    };

    const int xr = ((lane & 31) >> 2) & 3;
    const int hi = lane >> 5;

    loadW(0);
    stageA(0, 0);
    dequant(0);
    __syncthreads();

    for (int kt = 0; kt < KIT; ++kt) {
        const int cb = kt & 1, nb = cb ^ 1;
        const bool more = (kt + 1 < KIT);

        if (more) {
            loadW((kt + 1) * BK);
            stageA((kt + 1) * BK, nb);
        }

#pragma unroll
        for (int t = 0; t < BK / 16; ++t) {
            bf16x8 af[MI];
#pragma unroll
            for (int mi = 0; mi < MI; ++mi)
                af[mi] = *(const bf16x8*)(&sA[cb][(wv * RPW + mi * 32 + (lane & 31)) * BK
                                                  + (((t * 2 + hi) ^ xr) * 8)]);
#pragma unroll
            for (int mt = 0; mt < NMAT; ++mt) {
                bf16x8 bv = *(const bf16x8*)(&sB[cb][mt][(lane & 31) * SBS
                                                         + t * 16 + hi * 8]);
#pragma unroll
                for (int mi = 0; mi < MI; ++mi)
                    acc[mt][mi] = __builtin_amdgcn_mfma_f32_32x32x16_bf16(
                        af[mi], bv, acc[mt][mi], 0, 0, 0);
            }
        }

        if (more) dequant(nb);
        __syncthreads();
    }

    const int cbl = lane & 31;
    const int rq  = (lane >> 5) * 4;
#pragma unroll
    for (int mi = 0; mi < MI; ++mi)
#pragma unroll
        for (int r = 0; r < 16; ++r) {
            const int row = m0 + wv * RPW + mi * 32 + rq + (r & 3) + ((r >> 2) << 3);
            const size_t idx = (size_t)row * NT + (n0 + cbl);
            if constexpr (NMAT == 2) {
                const float g = acc[0][mi][r];
                const float u = acc[1][mi][r];
                const float d = g / (1.0f + __expf(-g)) * u;
                ((bf16*)OUTp)[idx] = (bf16)d;
            } else {
                ((float*)OUTp)[idx] = acc[0][mi][r];
            }
        }
}

extern "C" void kernel_launch(void* const* d_in, const int* in_sizes, int n_in,
                              void* d_out, int out_size, void* d_ws, size_t ws_size,
                              hipStream_t stream) {
    (void)in_sizes; (void)n_in; (void)out_size;

    const float* x   = (const float*)d_in[0];
    const float* gw  = (const float*)d_in[1];
    const float* gsu = (const float*)d_in[2];
    const float* gsv = (const float*)d_in[3];
    const float* uw  = (const float*)d_in[4];
    const float* usu = (const float*)d_in[5];
    const float* usv = (const float*)d_in[6];
    const float* dw  = (const float*)d_in[7];
    const float* dsu = (const float*)d_in[8];
    const float* dsv = (const float*)d_in[9];

    const size_t XBF = (size_t)1024 * 4096 * 2;     // x in bf16
    const size_t DSW = (size_t)1024 * 14336 * 2;    // swiglu out, bf16
    const size_t WSZ = (size_t)14336 * 4096 * 2;    // one dequantized weight matrix
    const size_t REQ = XBF + DSW + 3 * WSZ;         // ~372 MB

    bf16* x_bf = (bf16*)d_ws;
    bf16* d_sw = (bf16*)((char*)d_ws + XBF);
    float* out = (float*)d_out;

    // K0: x -> bf16  (4.19M elems, 8/thread)
    cvt_bf16_kernel<<<2048, 256, 0, stream>>>(x, x_bf);

    if (ws_size >= REQ) {
        bf16* Wg = (bf16*)((char*)d_ws + XBF + DSW);
        bf16* Wu = (bf16*)((char*)Wg + WSZ);
        bf16* Wd = (bf16*)((char*)Wu + WSZ);

        // Pre-pass: dequantize all three weight matrices to bf16 (memory-bound).
        dequant_kernel<<<dim3(4, 14336), 256, 0, stream>>>(gw, gsu, gsv, Wg, 4096);
        dequant_kernel<<<dim3(4, 14336), 256, 0, stream>>>(uw, usu, usv, Wu, 4096);
        dequant_kernel<<<dim3(14, 4096), 256, 0, stream>>>(dw, dsu, dsv, Wd, 14336);

        // K1: fused gate+up+swiglu. BM=256,BK=32,NBUF=3; grid 4x224=896 (%8==0).
        gemm_bf16<256, 32, 4096, 2, 3, 2><<<896, 256, 0, stream>>>(
            x_bf, Wg, Wu, d_sw, 14336);

        // K2: down. BM=128,BK=64,NBUF=3; grid 8x64=512 (%8==0).
        gemm_bf16<128, 64, 14336, 1, 3, 3><<<512, 256, 0, stream>>>(
            d_sw, Wd, nullptr, out, 4096);
    } else {
        // Fallback: fused-dequant path (workspace too small for weight pre-pass).
        mlp_gemm<512, 4096, 2><<<dim3(2, 448), 256, 0, stream>>>(
            x_bf, gw, gsu, gsv, uw, usu, usv, d_sw, 14336);
        mlp_gemm<512, 14336, 1><<<dim3(2, 128), 256, 0, stream>>>(
            d_sw, dw, dsu, dsv, nullptr, nullptr, nullptr, out, 4096);
    }
}